// Round 6
// baseline (228.516 us; speedup 1.0000x reference)
//
#include <hip/hip_runtime.h>
#include <hip/hip_bf16.h>
#include <math.h>

#define S 4096
#define D 512
#define H 8
#define DK 64
#define WIN 128

typedef __attribute__((ext_vector_type(8))) short bf16x8;
typedef __attribute__((ext_vector_type(4))) float f32x4;

__device__ __forceinline__ unsigned short f2bf(float f) {
    __hip_bfloat16 h = __float2bfloat16(f);
    return *(unsigned short*)&h;
}

// ---------------------------------------------------------------------------
// fp32 -> bf16 conversion (x). 8 elems/thread.
// ---------------------------------------------------------------------------
__global__ __launch_bounds__(256) void conv_bf16_kernel(
    const float* __restrict__ in, unsigned short* __restrict__ out, int n)
{
    const int i = (blockIdx.x * 256 + threadIdx.x) * 8;
    if (i >= n) return;
    float4 a = *(const float4*)&in[i];
    float4 b = *(const float4*)&in[i + 4];
    ushort4 o0 = {f2bf(a.x), f2bf(a.y), f2bf(a.z), f2bf(a.w)};
    ushort4 o1 = {f2bf(b.x), f2bf(b.y), f2bf(b.z), f2bf(b.w)};
    *(ushort4*)&out[i]     = o0;
    *(ushort4*)&out[i + 4] = o1;
}

// ---------------------------------------------------------------------------
// MFMA GEMM: C[m][n] = sum_e A[m][e]*W[n][e] + bias[n]
// ---------------------------------------------------------------------------
__device__ __forceinline__ void mfma_gemm_body(
    const unsigned short* __restrict__ A,
    const float* __restrict__ W,
    const float* __restrict__ bias,
    float* __restrict__ C,
    unsigned short* __restrict__ CB)
{
    __shared__ unsigned short Bs[64][520];

    const int tid  = threadIdx.x;
    const int m0   = blockIdx.x * 128;
    const int n0   = blockIdx.y * 64;
    const int wv   = tid >> 6;
    const int lane = tid & 63;
    const int l16  = lane & 15;
    const int klo  = (lane >> 4) * 8;

    #pragma unroll
    for (int it = 0; it < 16; ++it) {
        const int c   = tid + it * 256;
        const int row = c >> 6;
        const int kc  = (c & 63) * 8;
        const float* src = &W[(size_t)(n0 + row) * 512 + kc];
        float4 a = *(const float4*)&src[0];
        float4 b = *(const float4*)&src[4];
        ushort4 o0 = {f2bf(a.x), f2bf(a.y), f2bf(a.z), f2bf(a.w)};
        ushort4 o1 = {f2bf(b.x), f2bf(b.y), f2bf(b.z), f2bf(b.w)};
        *(ushort4*)&Bs[row][kc]     = o0;
        *(ushort4*)&Bs[row][kc + 4] = o1;
    }
    __syncthreads();

    const unsigned short* arow0 = &A[(size_t)(m0 + wv * 32 + l16) * 512 + klo];
    const unsigned short* arow1 = arow0 + 16 * 512;

    f32x4 acc[2][4];
    #pragma unroll
    for (int r = 0; r < 2; ++r)
        #pragma unroll
        for (int nf = 0; nf < 4; ++nf)
            acc[r][nf] = (f32x4){0.f, 0.f, 0.f, 0.f};

    #pragma unroll 4
    for (int kb = 0; kb < 512; kb += 32) {
        bf16x8 a0 = *(const bf16x8*)&arow0[kb];
        bf16x8 a1 = *(const bf16x8*)&arow1[kb];
        #pragma unroll
        for (int nf = 0; nf < 4; ++nf) {
            bf16x8 b = *(const bf16x8*)&Bs[nf * 16 + l16][kb + klo];
            acc[0][nf] = __builtin_amdgcn_mfma_f32_16x16x32_bf16(a0, b, acc[0][nf], 0, 0, 0);
            acc[1][nf] = __builtin_amdgcn_mfma_f32_16x16x32_bf16(a1, b, acc[1][nf], 0, 0, 0);
        }
    }

    const int r0 = (lane >> 4) * 4;
    #pragma unroll
    for (int r = 0; r < 2; ++r) {
        #pragma unroll
        for (int nf = 0; nf < 4; ++nf) {
            const int col = n0 + nf * 16 + l16;
            const float bb = bias[col];
            #pragma unroll
            for (int vv = 0; vv < 4; ++vv) {
                const int row = m0 + wv * 32 + r * 16 + r0 + vv;
                const float val = acc[r][nf][vv] + bb;
                if (C)  C [(size_t)row * 512 + col] = val;
                if (CB) CB[(size_t)row * 512 + col] = f2bf(val);
            }
        }
    }
}

__global__ __launch_bounds__(256) void proj3_kernel(
    const unsigned short* __restrict__ xb,
    const float* __restrict__ wq, const float* __restrict__ bq,
    const float* __restrict__ wk, const float* __restrict__ bk,
    const float* __restrict__ wv, const float* __restrict__ bv,
    float* __restrict__ q, float* __restrict__ k, float* __restrict__ v)
{
    const float* W; const float* b; float* C;
    if (blockIdx.z == 0)      { W = wq; b = bq; C = q; }
    else if (blockIdx.z == 1) { W = wk; b = bk; C = k; }
    else                      { W = wv; b = bv; C = v; }
    mfma_gemm_body(xb, W, b, C, nullptr);
}

__global__ __launch_bounds__(256) void outproj_kernel(
    const unsigned short* __restrict__ ctxb,
    const float* __restrict__ wo, const float* __restrict__ bo,
    float* __restrict__ out)
{
    mfma_gemm_body(ctxb, wo, bo, out, nullptr);
}

// ---------------------------------------------------------------------------
// Band attention weights: scores -> softmax -> COMPACT probs buffer.
// Pc[h][i][272]: normalized probs for cols [start, start+272),
// start = max(i-128,0)&~3; zeros at out-of-band slots. 34 MB total.
// ---------------------------------------------------------------------------
__global__ __launch_bounds__(256) void band_attn_kernel(
    const float* __restrict__ q, const float* __restrict__ k,
    float* __restrict__ Pc)
{
    __shared__ float Qs[64][68];    // transposed: Qs[d][row]
    __shared__ float Ks[64][68];    // transposed: Ks[d][col]
    __shared__ float P[64][336];    // band scores, local window coords
    __shared__ float rinvs[64];

    const int tid = threadIdx.x;
    const int h  = blockIdx.y;
    const int q0 = blockIdx.x * 64;
    const int w0 = q0 - 128;

    const int lr = tid >> 2;
    const int ld = (tid & 3) * 16;

    #pragma unroll
    for (int t = 0; t < 4; ++t) {
        float4 v4 = *(const float4*)&q[(size_t)(q0 + lr) * 512 + h * 64 + ld + t * 4];
        Qs[ld + t * 4 + 0][lr] = v4.x;
        Qs[ld + t * 4 + 1][lr] = v4.y;
        Qs[ld + t * 4 + 2][lr] = v4.z;
        Qs[ld + t * 4 + 3][lr] = v4.w;
    }

    const int rr = (tid & 15) * 4;
    const int cc = (tid >> 4) * 4;

    for (int ch = 0; ch < 5; ++ch) {
        const int c0 = w0 + ch * 64;
        if (c0 < 0 || c0 >= S) continue;
        __syncthreads();
        #pragma unroll
        for (int t = 0; t < 4; ++t) {
            float4 v4 = *(const float4*)&k[(size_t)(c0 + lr) * 512 + h * 64 + ld + t * 4];
            Ks[ld + t * 4 + 0][lr] = v4.x;
            Ks[ld + t * 4 + 1][lr] = v4.y;
            Ks[ld + t * 4 + 2][lr] = v4.z;
            Ks[ld + t * 4 + 3][lr] = v4.w;
        }
        __syncthreads();

        float sc[4][4] = {};
        #pragma unroll 8
        for (int d = 0; d < 64; ++d) {
            float4 qv = *(const float4*)&Qs[d][rr];
            float4 kv = *(const float4*)&Ks[d][cc];
            const float qa[4] = {qv.x, qv.y, qv.z, qv.w};
            const float ka[4] = {kv.x, kv.y, kv.z, kv.w};
            #pragma unroll
            for (int i = 0; i < 4; ++i)
                #pragma unroll
                for (int j = 0; j < 4; ++j)
                    sc[i][j] = fmaf(qa[i], ka[j], sc[i][j]);
        }

        #pragma unroll
        for (int i = 0; i < 4; ++i) {
            float4 o = {sc[i][0] * 0.125f, sc[i][1] * 0.125f,
                        sc[i][2] * 0.125f, sc[i][3] * 0.125f};
            *(float4*)&P[rr + i][ch * 64 + cc] = o;
        }
    }
    __syncthreads();

    {
        const int r  = tid >> 2;
        const int l2 = tid & 3;
        const int i  = q0 + r;
        const int lo = max(i - WIN, 0) - w0;
        const int hi = min(i + WIN, S - 1) - w0;

        float m = -1e30f;
        for (int c = lo + l2; c <= hi; c += 4) m = fmaxf(m, P[r][c]);
        m = fmaxf(m, __shfl_xor(m, 1));
        m = fmaxf(m, __shfl_xor(m, 2));

        float sum = 0.f;
        for (int c = lo + l2; c <= hi; c += 4) {
            float e = __expf(P[r][c] - m);
            P[r][c] = e;
            sum += e;
        }
        sum += __shfl_xor(sum, 1);
        sum += __shfl_xor(sum, 2);
        if (l2 == 0) rinvs[r] = 1.0f / sum;
    }
    __syncthreads();

    // ---- write compact windows: 64 rows x 68 float4 slots = 17 iterations
    float* pcb = Pc + ((size_t)h * S + q0) * 272;
    #pragma unroll 1
    for (int it = 0; it < 17; ++it) {
        const int slot = it * 256 + tid;
        const int r = (int)((unsigned)slot / 68u);
        const int j = (slot - r * 68) * 4;
        const int i = q0 + r;
        const int start = max(i - WIN, 0) & ~3;
        const int lo = max(i - WIN, 0) - w0;
        const int hi = min(i + WIN, S - 1) - w0;
        const int lc = start + j - w0;
        const float rv = rinvs[r];
        float4 o;
        if (lc >= lo && lc + 3 <= hi) {
            float4 p = *(const float4*)&P[r][lc];
            o.x = p.x * rv; o.y = p.y * rv; o.z = p.z * rv; o.w = p.w * rv;
        } else {
            o.x = (lc + 0 >= lo && lc + 0 <= hi) ? P[r][lc + 0] * rv : 0.f;
            o.y = (lc + 1 >= lo && lc + 1 <= hi) ? P[r][lc + 1] * rv : 0.f;
            o.z = (lc + 2 >= lo && lc + 2 <= hi) ? P[r][lc + 2] * rv : 0.f;
            o.w = (lc + 3 >= lo && lc + 3 <= hi) ? P[r][lc + 3] * rv : 0.f;
        }
        *(float4*)&pcb[(size_t)r * 272 + j] = o;
    }
}

// ---------------------------------------------------------------------------
// Stream attn: one wave per row. Read 272-col window from Pc (L2/L3-warm),
// write the full 4096-col row (zeros outside window). Pure coalesced stores.
// NOTE wave=64: window is 68 float4 slots -> lanes 0..3 load a second slot.
// ---------------------------------------------------------------------------
__global__ __launch_bounds__(256) void attn_write_kernel(
    const float* __restrict__ Pc, float* __restrict__ attn)
{
    __shared__ float win[4][272];
    const int w    = threadIdx.x >> 6;
    const int lane = threadIdx.x & 63;
    const int rowid = blockIdx.x * 4 + w;          // h*S + i
    const int i = rowid & (S - 1);
    const int start = max(i - WIN, 0) & ~3;

    const float* pcrow = &Pc[(size_t)rowid * 272];
    *(float4*)&win[w][lane * 4] = *(const float4*)&pcrow[lane * 4];
    if (lane < 4)
        *(float4*)&win[w][(lane + 64) * 4] = *(const float4*)&pcrow[(lane + 64) * 4];
    __syncthreads();

    float* rowp = attn + (size_t)rowid * S;
    #pragma unroll
    for (int it = 0; it < 16; ++it) {
        const int col = (it * 64 + lane) * 4;
        float4 o = make_float4(0.f, 0.f, 0.f, 0.f);
        if (col >= start && col < start + 272)
            o = *(const float4*)&win[w][col - start];
        *(float4*)&rowp[col] = o;
    }
}

// ---------------------------------------------------------------------------
// PV via MFMA: ctx[64][64] = P[64][320] x V[320][64] per (q-block, head).
// P read from compact Pc (fp32 -> bf16), V transposed into LDS as bf16.
// ---------------------------------------------------------------------------
__global__ __launch_bounds__(256) void band_pv_kernel(
    const float* __restrict__ Pc, const float* __restrict__ v,
    unsigned short* __restrict__ ctxb)
{
    __shared__ unsigned short Pb [64][328];   // Pb[row][local col]
    __shared__ unsigned short VsT[64][328];   // VsT[d][local col]
    const int tid = threadIdx.x;
    const int h  = blockIdx.y;
    const int q0 = blockIdx.x * 64;
    const int w0 = q0 - 128;

    const int lr = tid >> 2;           // 0..63
    const int ld = (tid & 3) * 16;     // 0,16,32,48
    const float* pcb = Pc + ((size_t)h * S + q0) * 272;
    const int start = max(q0 + lr - WIN, 0) & ~3;   // per-row window start

    for (int ch = 0; ch < 5; ++ch) {
        const int c0 = w0 + ch * 64;
        if (c0 >= 0 && c0 < S) {
            #pragma unroll
            for (int t = 0; t < 4; ++t) {
                const int col = c0 + ld + t * 4;
                float4 p4 = make_float4(0.f, 0.f, 0.f, 0.f);
                if (col >= start && col < start + 272)
                    p4 = *(const float4*)&pcb[(size_t)lr * 272 + (col - start)];
                ushort4 o = {f2bf(p4.x), f2bf(p4.y), f2bf(p4.z), f2bf(p4.w)};
                *(ushort4*)&Pb[lr][ch * 64 + ld + t * 4] = o;
                float4 v4 = *(const float4*)&v[(size_t)(c0 + lr) * 512 + h * 64 + ld + t * 4];
                VsT[ld + t * 4 + 0][ch * 64 + lr] = f2bf(v4.x);
                VsT[ld + t * 4 + 1][ch * 64 + lr] = f2bf(v4.y);
                VsT[ld + t * 4 + 2][ch * 64 + lr] = f2bf(v4.z);
                VsT[ld + t * 4 + 3][ch * 64 + lr] = f2bf(v4.w);
            }
        } else {
            #pragma unroll
            for (int t = 0; t < 4; ++t) {
                ushort4 z4 = {0, 0, 0, 0};
                *(ushort4*)&Pb[lr][ch * 64 + ld + t * 4] = z4;
                VsT[ld + t * 4 + 0][ch * 64 + lr] = 0;
                VsT[ld + t * 4 + 1][ch * 64 + lr] = 0;
                VsT[ld + t * 4 + 2][ch * 64 + lr] = 0;
                VsT[ld + t * 4 + 3][ch * 64 + lr] = 0;
            }
        }
    }
    __syncthreads();

    const int wv   = tid >> 6;
    const int lane = tid & 63;
    const int l16  = lane & 15;
    const int klo  = (lane >> 4) * 8;

    f32x4 acc[4];
    #pragma unroll
    for (int nf = 0; nf < 4; ++nf) acc[nf] = (f32x4){0.f, 0.f, 0.f, 0.f};

    #pragma unroll
    for (int ks = 0; ks < 10; ++ks) {
        bf16x8 a = *(const bf16x8*)&Pb[wv * 16 + l16][ks * 32 + klo];
        #pragma unroll
        for (int nf = 0; nf < 4; ++nf) {
            bf16x8 b = *(const bf16x8*)&VsT[nf * 16 + l16][ks * 32 + klo];
            acc[nf] = __builtin_amdgcn_mfma_f32_16x16x32_bf16(a, b, acc[nf], 0, 0, 0);
        }
    }

    const int r0 = (lane >> 4) * 4;
    #pragma unroll
    for (int nf = 0; nf < 4; ++nf) {
        #pragma unroll
        for (int vv = 0; vv < 4; ++vv) {
            const int row = q0 + wv * 16 + r0 + vv;
            ctxb[(size_t)row * 512 + h * 64 + nf * 16 + l16] = f2bf(acc[nf][vv]);
        }
    }
}

// ---------------------------------------------------------------------------
extern "C" void kernel_launch(void* const* d_in, const int* in_sizes, int n_in,
                              void* d_out, int out_size, void* d_ws, size_t ws_size,
                              hipStream_t stream)
{
    (void)in_sizes; (void)n_in; (void)out_size; (void)ws_size;
    const float* x  = (const float*)d_in[0];
    const float* wq = (const float*)d_in[1];
    const float* bq = (const float*)d_in[2];
    const float* wk = (const float*)d_in[3];
    const float* bk = (const float*)d_in[4];
    const float* wv = (const float*)d_in[5];
    const float* bv = (const float*)d_in[6];
    const float* wo = (const float*)d_in[7];
    const float* bo = (const float*)d_in[8];

    float* out  = (float*)d_out;                       // (S, D)
    float* attn = out + (size_t)S * D;                 // (H, S, S)

    float* q = (float*)d_ws;                           // 8 MB each
    float* k = q + (size_t)S * D;
    float* v = k + (size_t)S * D;
    unsigned short* xb   = (unsigned short*)(v + (size_t)S * D);  // 4 MB
    unsigned short* ctxb = xb + (size_t)S * D;                    // 4 MB
    float* Pc = (float*)(ctxb + (size_t)S * D);                   // 34 MB compact probs

    conv_bf16_kernel<<<(S * D) / (256 * 8), 256, 0, stream>>>(x, xb, S * D);
    proj3_kernel<<<dim3(32, 8, 3), 256, 0, stream>>>(xb, wq, bq, wk, bk, wv, bv, q, k, v);
    band_attn_kernel<<<dim3(64, 8), 256, 0, stream>>>(q, k, Pc);
    band_pv_kernel<<<dim3(64, 8), 256, 0, stream>>>(Pc, v, ctxb);
    attn_write_kernel<<<(H * S) / 4, 256, 0, stream>>>(Pc, attn);
    outproj_kernel<<<dim3(32, 8), 256, 0, stream>>>(ctxb, wo, bo, out);
}

// Round 8
// 182.357 us; speedup vs baseline: 1.2531x; 1.2531x over previous
//
#include <hip/hip_runtime.h>
#include <hip/hip_bf16.h>
#include <math.h>

#define S 4096
#define D 512
#define H 8
#define DK 64
#define WIN 128

typedef __attribute__((ext_vector_type(8))) short bf16x8;
typedef __attribute__((ext_vector_type(4))) float f32x4;

__device__ __forceinline__ unsigned short f2bf(float f) {
    __hip_bfloat16 h = __float2bfloat16(f);
    return *(unsigned short*)&h;
}

// ---------------------------------------------------------------------------
// fp32 -> bf16 conversion (x). 8 elems/thread.
// ---------------------------------------------------------------------------
__global__ __launch_bounds__(256) void conv_bf16_kernel(
    const float* __restrict__ in, unsigned short* __restrict__ out, int n)
{
    const int i = (blockIdx.x * 256 + threadIdx.x) * 8;
    if (i >= n) return;
    float4 a = *(const float4*)&in[i];
    float4 b = *(const float4*)&in[i + 4];
    ushort4 o0 = {f2bf(a.x), f2bf(a.y), f2bf(a.z), f2bf(a.w)};
    ushort4 o1 = {f2bf(b.x), f2bf(b.y), f2bf(b.z), f2bf(b.w)};
    *(ushort4*)&out[i]     = o0;
    *(ushort4*)&out[i + 4] = o1;
}

// ---------------------------------------------------------------------------
// MFMA GEMM: C[m][n] = sum_e A[m][e]*W[n][e] + bias[n]
// ---------------------------------------------------------------------------
__device__ __forceinline__ void mfma_gemm_body(
    const unsigned short* __restrict__ A,
    const float* __restrict__ W,
    const float* __restrict__ bias,
    float* __restrict__ C,
    unsigned short* __restrict__ CB)
{
    __shared__ unsigned short Bs[64][520];

    const int tid  = threadIdx.x;
    const int m0   = blockIdx.x * 128;
    const int n0   = blockIdx.y * 64;
    const int wv   = tid >> 6;
    const int lane = tid & 63;
    const int l16  = lane & 15;
    const int klo  = (lane >> 4) * 8;

    #pragma unroll
    for (int it = 0; it < 16; ++it) {
        const int c   = tid + it * 256;
        const int row = c >> 6;
        const int kc  = (c & 63) * 8;
        const float* src = &W[(size_t)(n0 + row) * 512 + kc];
        float4 a = *(const float4*)&src[0];
        float4 b = *(const float4*)&src[4];
        ushort4 o0 = {f2bf(a.x), f2bf(a.y), f2bf(a.z), f2bf(a.w)};
        ushort4 o1 = {f2bf(b.x), f2bf(b.y), f2bf(b.z), f2bf(b.w)};
        *(ushort4*)&Bs[row][kc]     = o0;
        *(ushort4*)&Bs[row][kc + 4] = o1;
    }
    __syncthreads();

    const unsigned short* arow0 = &A[(size_t)(m0 + wv * 32 + l16) * 512 + klo];
    const unsigned short* arow1 = arow0 + 16 * 512;

    f32x4 acc[2][4];
    #pragma unroll
    for (int r = 0; r < 2; ++r)
        #pragma unroll
        for (int nf = 0; nf < 4; ++nf)
            acc[r][nf] = (f32x4){0.f, 0.f, 0.f, 0.f};

    #pragma unroll 4
    for (int kb = 0; kb < 512; kb += 32) {
        bf16x8 a0 = *(const bf16x8*)&arow0[kb];
        bf16x8 a1 = *(const bf16x8*)&arow1[kb];
        #pragma unroll
        for (int nf = 0; nf < 4; ++nf) {
            bf16x8 b = *(const bf16x8*)&Bs[nf * 16 + l16][kb + klo];
            acc[0][nf] = __builtin_amdgcn_mfma_f32_16x16x32_bf16(a0, b, acc[0][nf], 0, 0, 0);
            acc[1][nf] = __builtin_amdgcn_mfma_f32_16x16x32_bf16(a1, b, acc[1][nf], 0, 0, 0);
        }
    }

    const int r0 = (lane >> 4) * 4;
    #pragma unroll
    for (int r = 0; r < 2; ++r) {
        #pragma unroll
        for (int nf = 0; nf < 4; ++nf) {
            const int col = n0 + nf * 16 + l16;
            const float bb = bias[col];
            #pragma unroll
            for (int vv = 0; vv < 4; ++vv) {
                const int row = m0 + wv * 32 + r * 16 + r0 + vv;
                const float val = acc[r][nf][vv] + bb;
                if (C)  C [(size_t)row * 512 + col] = val;
                if (CB) CB[(size_t)row * 512 + col] = f2bf(val);
            }
        }
    }
}

__global__ __launch_bounds__(256) void proj3_kernel(
    const unsigned short* __restrict__ xb,
    const float* __restrict__ wq, const float* __restrict__ bq,
    const float* __restrict__ wk, const float* __restrict__ bk,
    const float* __restrict__ wv, const float* __restrict__ bv,
    float* __restrict__ q, float* __restrict__ k, float* __restrict__ v)
{
    const float* W; const float* b; float* C;
    if (blockIdx.z == 0)      { W = wq; b = bq; C = q; }
    else if (blockIdx.z == 1) { W = wk; b = bk; C = k; }
    else                      { W = wv; b = bv; C = v; }
    mfma_gemm_body(xb, W, b, C, nullptr);
}

__global__ __launch_bounds__(256) void outproj_kernel(
    const unsigned short* __restrict__ ctxb,
    const float* __restrict__ wo, const float* __restrict__ bo,
    float* __restrict__ out)
{
    mfma_gemm_body(ctxb, wo, bo, out, nullptr);
}

// ---------------------------------------------------------------------------
// Fused band attention: scores -> softmax -> full-row coalesced write (zeros
// outside band). QB=32 rows/block -> ~70 KB LDS -> 2 blocks/CU, so one
// block's compute overlaps another's store drain. Grid (128, 8).
// NOTE: q0 is 32-aligned, so 64-wide chunks may PARTIALLY overlap [0,S):
// compute any overlapping chunk (clamped key rows); fully-outside chunks skip.
// ---------------------------------------------------------------------------
__global__ __launch_bounds__(256) void band_attn_kernel(
    const float* __restrict__ q, const float* __restrict__ k,
    float* __restrict__ attn)
{
    __shared__ float Qs[64][36];    // Qs[d][row], 32 rows          (9.2 KB)
    __shared__ float Ks[64][68];    // Ks[d][col], 64-col chunk     (17.4 KB)
    __shared__ float P[32][336];    // band scores, local coords    (43 KB)
    __shared__ float rinvs[32];

    const int tid = threadIdx.x;
    const int h  = blockIdx.y;
    const int q0 = blockIdx.x * 32;
    const int w0 = q0 - 128;

    // ---- Q staging: thread (row = tid&31, db = (tid>>5)*8) ----
    {
        const int row = tid & 31;
        const int db  = (tid >> 5) * 8;
        const float* src = &q[(size_t)(q0 + row) * 512 + h * 64 + db];
        float4 a = *(const float4*)&src[0];
        float4 b = *(const float4*)&src[4];
        Qs[db + 0][row] = a.x; Qs[db + 1][row] = a.y;
        Qs[db + 2][row] = a.z; Qs[db + 3][row] = a.w;
        Qs[db + 4][row] = b.x; Qs[db + 5][row] = b.y;
        Qs[db + 6][row] = b.z; Qs[db + 7][row] = b.w;
    }

    const int lr = tid >> 2;           // K stage: col 0..63
    const int ld = (tid & 3) * 16;     // K stage: 16 d's
    const int rr = (tid & 15) * 2;     // score rows (2 per thread)
    const int cc = (tid >> 4) * 4;     // score cols (4 per thread)

    for (int ch = 0; ch < 5; ++ch) {
        const int c0 = w0 + ch * 64;
        if (c0 + 64 <= 0 || c0 >= S) continue;   // skip only fully-outside chunks
        __syncthreads();
        {
            const int krow = min(max(c0 + lr, 0), S - 1);   // clamp partial chunks
            #pragma unroll
            for (int t = 0; t < 4; ++t) {
                float4 v4 = *(const float4*)&k[(size_t)krow * 512 + h * 64 + ld + t * 4];
                Ks[ld + t * 4 + 0][lr] = v4.x;
                Ks[ld + t * 4 + 1][lr] = v4.y;
                Ks[ld + t * 4 + 2][lr] = v4.z;
                Ks[ld + t * 4 + 3][lr] = v4.w;
            }
        }
        __syncthreads();

        float sc[2][4] = {};
        #pragma unroll 8
        for (int d = 0; d < 64; ++d) {
            const float qa0 = Qs[d][rr];
            const float qa1 = Qs[d][rr + 1];
            float4 kv = *(const float4*)&Ks[d][cc];
            const float ka[4] = {kv.x, kv.y, kv.z, kv.w};
            #pragma unroll
            for (int j = 0; j < 4; ++j) {
                sc[0][j] = fmaf(qa0, ka[j], sc[0][j]);
                sc[1][j] = fmaf(qa1, ka[j], sc[1][j]);
            }
        }

        #pragma unroll
        for (int i = 0; i < 2; ++i) {
            float4 o = {sc[i][0] * 0.125f, sc[i][1] * 0.125f,
                        sc[i][2] * 0.125f, sc[i][3] * 0.125f};
            *(float4*)&P[rr + i][ch * 64 + cc] = o;
        }
    }
    __syncthreads();

    // ---- per-row softmax over band (8 lanes per row) ----
    {
        const int r  = tid >> 3;
        const int l8 = tid & 7;
        const int i  = q0 + r;
        const int lo = max(i - WIN, 0) - w0;
        const int hi = min(i + WIN, S - 1) - w0;

        float m = -1e30f;
        for (int c = lo + l8; c <= hi; c += 8) m = fmaxf(m, P[r][c]);
        m = fmaxf(m, __shfl_xor(m, 1));
        m = fmaxf(m, __shfl_xor(m, 2));
        m = fmaxf(m, __shfl_xor(m, 4));

        float sum = 0.f;
        for (int c = lo + l8; c <= hi; c += 8) {
            float e = __expf(P[r][c] - m);
            P[r][c] = e;
            sum += e;
        }
        sum += __shfl_xor(sum, 1);
        sum += __shfl_xor(sum, 2);
        sum += __shfl_xor(sum, 4);
        if (l8 == 0) rinvs[r] = 1.0f / sum;
    }
    __syncthreads();

    // ---- write full rows, coalesced: 4096 floats/row, zeros outside band
    float* rowbase = attn + (size_t)h * S * S;
    #pragma unroll 1
    for (int r = 0; r < 32; ++r) {
        const int i = q0 + r;
        float* rowp = rowbase + (size_t)i * S;
        const int lo = max(i - WIN, 0) - w0;
        const int hi = min(i + WIN, S - 1) - w0;
        const float rv = rinvs[r];
        #pragma unroll
        for (int t = 0; t < 4; ++t) {
            const int c4 = (tid + t * 256) << 2;
            const int lc = c4 - w0;
            float4 o;
            if (lc >= lo && lc + 3 <= hi) {
                float4 p = *(const float4*)&P[r][lc];
                o.x = p.x * rv; o.y = p.y * rv; o.z = p.z * rv; o.w = p.w * rv;
            } else if (lc + 3 < lo || lc > hi) {
                o = make_float4(0.f, 0.f, 0.f, 0.f);
            } else {
                o.x = (lc + 0 >= lo && lc + 0 <= hi) ? P[r][lc + 0] * rv : 0.f;
                o.y = (lc + 1 >= lo && lc + 1 <= hi) ? P[r][lc + 1] * rv : 0.f;
                o.z = (lc + 2 >= lo && lc + 2 <= hi) ? P[r][lc + 2] * rv : 0.f;
                o.w = (lc + 3 >= lo && lc + 3 <= hi) ? P[r][lc + 3] * rv : 0.f;
            }
            *(float4*)&rowp[c4] = o;
        }
    }
}

// ---------------------------------------------------------------------------
// PV via MFMA: ctx[64][64] = P[64][320] x V[320][64] per (q-block, head).
// P read from attn rows (fp32 -> bf16), V transposed into LDS as bf16.
// q0 is 64-aligned here, so chunks are never partial.
// ---------------------------------------------------------------------------
__global__ __launch_bounds__(256) void band_pv_kernel(
    const float* __restrict__ attn, const float* __restrict__ v,
    unsigned short* __restrict__ ctxb)
{
    __shared__ unsigned short Pb [64][328];   // Pb[row][local col]
    __shared__ unsigned short VsT[64][328];   // VsT[d][local col]
    const int tid = threadIdx.x;
    const int h  = blockIdx.y;
    const int q0 = blockIdx.x * 64;
    const int w0 = q0 - 128;

    const int lr = tid >> 2;           // 0..63
    const int ld = (tid & 3) * 16;     // 0,16,32,48
    const float* aptr = attn + (size_t)h * S * S;

    for (int ch = 0; ch < 5; ++ch) {
        const int c0 = w0 + ch * 64;
        if (c0 >= 0 && c0 < S) {
            #pragma unroll
            for (int t = 0; t < 4; ++t) {
                float4 p4 = *(const float4*)&aptr[(size_t)(q0 + lr) * S + c0 + ld + t * 4];
                ushort4 o = {f2bf(p4.x), f2bf(p4.y), f2bf(p4.z), f2bf(p4.w)};
                *(ushort4*)&Pb[lr][ch * 64 + ld + t * 4] = o;
                float4 v4 = *(const float4*)&v[(size_t)(c0 + lr) * 512 + h * 64 + ld + t * 4];
                VsT[ld + t * 4 + 0][ch * 64 + lr] = f2bf(v4.x);
                VsT[ld + t * 4 + 1][ch * 64 + lr] = f2bf(v4.y);
                VsT[ld + t * 4 + 2][ch * 64 + lr] = f2bf(v4.z);
                VsT[ld + t * 4 + 3][ch * 64 + lr] = f2bf(v4.w);
            }
        } else {
            #pragma unroll
            for (int t = 0; t < 4; ++t) {
                ushort4 z4 = {0, 0, 0, 0};
                *(ushort4*)&Pb[lr][ch * 64 + ld + t * 4] = z4;
                VsT[ld + t * 4 + 0][ch * 64 + lr] = 0;
                VsT[ld + t * 4 + 1][ch * 64 + lr] = 0;
                VsT[ld + t * 4 + 2][ch * 64 + lr] = 0;
                VsT[ld + t * 4 + 3][ch * 64 + lr] = 0;
            }
        }
    }
    __syncthreads();

    const int wv   = tid >> 6;
    const int lane = tid & 63;
    const int l16  = lane & 15;
    const int klo  = (lane >> 4) * 8;

    f32x4 acc[4];
    #pragma unroll
    for (int nf = 0; nf < 4; ++nf) acc[nf] = (f32x4){0.f, 0.f, 0.f, 0.f};

    #pragma unroll
    for (int ks = 0; ks < 10; ++ks) {
        bf16x8 a = *(const bf16x8*)&Pb[wv * 16 + l16][ks * 32 + klo];
        #pragma unroll
        for (int nf = 0; nf < 4; ++nf) {
            bf16x8 b = *(const bf16x8*)&VsT[nf * 16 + l16][ks * 32 + klo];
            acc[nf] = __builtin_amdgcn_mfma_f32_16x16x32_bf16(a, b, acc[nf], 0, 0, 0);
        }
    }

    const int r0 = (lane >> 4) * 4;
    #pragma unroll
    for (int nf = 0; nf < 4; ++nf) {
        #pragma unroll
        for (int vv = 0; vv < 4; ++vv) {
            const int row = q0 + wv * 16 + r0 + vv;
            ctxb[(size_t)row * 512 + h * 64 + nf * 16 + l16] = f2bf(acc[nf][vv]);
        }
    }
}

// ---------------------------------------------------------------------------
extern "C" void kernel_launch(void* const* d_in, const int* in_sizes, int n_in,
                              void* d_out, int out_size, void* d_ws, size_t ws_size,
                              hipStream_t stream)
{
    (void)in_sizes; (void)n_in; (void)out_size; (void)ws_size;
    const float* x  = (const float*)d_in[0];
    const float* wq = (const float*)d_in[1];
    const float* bq = (const float*)d_in[2];
    const float* wk = (const float*)d_in[3];
    const float* bk = (const float*)d_in[4];
    const float* wv = (const float*)d_in[5];
    const float* bv = (const float*)d_in[6];
    const float* wo = (const float*)d_in[7];
    const float* bo = (const float*)d_in[8];

    float* out  = (float*)d_out;                       // (S, D)
    float* attn = out + (size_t)S * D;                 // (H, S, S)

    float* q = (float*)d_ws;                           // 8 MB each
    float* k = q + (size_t)S * D;
    float* v = k + (size_t)S * D;
    unsigned short* xb   = (unsigned short*)(v + (size_t)S * D);  // 4 MB
    unsigned short* ctxb = xb + (size_t)S * D;                    // 4 MB

    conv_bf16_kernel<<<(S * D) / (256 * 8), 256, 0, stream>>>(x, xb, S * D);
    proj3_kernel<<<dim3(32, 8, 3), 256, 0, stream>>>(xb, wq, bq, wk, bk, wv, bv, q, k, v);
    band_attn_kernel<<<dim3(128, 8), 256, 0, stream>>>(q, k, attn);
    band_pv_kernel<<<dim3(64, 8), 256, 0, stream>>>(attn, v, ctxb);
    outproj_kernel<<<dim3(32, 8), 256, 0, stream>>>(ctxb, wo, bo, out);
}

// Round 9
// 173.221 us; speedup vs baseline: 1.3192x; 1.0527x over previous
//
#include <hip/hip_runtime.h>
#include <hip/hip_bf16.h>
#include <math.h>

#define S 4096
#define D 512
#define H 8
#define DK 64
#define WIN 128

typedef __attribute__((ext_vector_type(8))) short bf16x8;
typedef __attribute__((ext_vector_type(4))) float f32x4;

__device__ __forceinline__ unsigned short f2bf(float f) {
    __hip_bfloat16 h = __float2bfloat16(f);
    return *(unsigned short*)&h;
}

// ---------------------------------------------------------------------------
// fp32 -> bf16 conversion (x). 8 elems/thread.
// ---------------------------------------------------------------------------
__global__ __launch_bounds__(256) void conv_bf16_kernel(
    const float* __restrict__ in, unsigned short* __restrict__ out, int n)
{
    const int i = (blockIdx.x * 256 + threadIdx.x) * 8;
    if (i >= n) return;
    float4 a = *(const float4*)&in[i];
    float4 b = *(const float4*)&in[i + 4];
    ushort4 o0 = {f2bf(a.x), f2bf(a.y), f2bf(a.z), f2bf(a.w)};
    ushort4 o1 = {f2bf(b.x), f2bf(b.y), f2bf(b.z), f2bf(b.w)};
    *(ushort4*)&out[i]     = o0;
    *(ushort4*)&out[i + 4] = o1;
}

// ---------------------------------------------------------------------------
// MFMA GEMM: C[m][n] = sum_e A[m][e]*W[n][e] + bias[n]
// ---------------------------------------------------------------------------
__device__ __forceinline__ void mfma_gemm_body(
    const unsigned short* __restrict__ A,
    const float* __restrict__ W,
    const float* __restrict__ bias,
    float* __restrict__ C,
    unsigned short* __restrict__ CB)
{
    __shared__ unsigned short Bs[64][520];

    const int tid  = threadIdx.x;
    const int m0   = blockIdx.x * 128;
    const int n0   = blockIdx.y * 64;
    const int wv   = tid >> 6;
    const int lane = tid & 63;
    const int l16  = lane & 15;
    const int klo  = (lane >> 4) * 8;

    #pragma unroll
    for (int it = 0; it < 16; ++it) {
        const int c   = tid + it * 256;
        const int row = c >> 6;
        const int kc  = (c & 63) * 8;
        const float* src = &W[(size_t)(n0 + row) * 512 + kc];
        float4 a = *(const float4*)&src[0];
        float4 b = *(const float4*)&src[4];
        ushort4 o0 = {f2bf(a.x), f2bf(a.y), f2bf(a.z), f2bf(a.w)};
        ushort4 o1 = {f2bf(b.x), f2bf(b.y), f2bf(b.z), f2bf(b.w)};
        *(ushort4*)&Bs[row][kc]     = o0;
        *(ushort4*)&Bs[row][kc + 4] = o1;
    }
    __syncthreads();

    const unsigned short* arow0 = &A[(size_t)(m0 + wv * 32 + l16) * 512 + klo];
    const unsigned short* arow1 = arow0 + 16 * 512;

    f32x4 acc[2][4];
    #pragma unroll
    for (int r = 0; r < 2; ++r)
        #pragma unroll
        for (int nf = 0; nf < 4; ++nf)
            acc[r][nf] = (f32x4){0.f, 0.f, 0.f, 0.f};

    #pragma unroll 4
    for (int kb = 0; kb < 512; kb += 32) {
        bf16x8 a0 = *(const bf16x8*)&arow0[kb];
        bf16x8 a1 = *(const bf16x8*)&arow1[kb];
        #pragma unroll
        for (int nf = 0; nf < 4; ++nf) {
            bf16x8 b = *(const bf16x8*)&Bs[nf * 16 + l16][kb + klo];
            acc[0][nf] = __builtin_amdgcn_mfma_f32_16x16x32_bf16(a0, b, acc[0][nf], 0, 0, 0);
            acc[1][nf] = __builtin_amdgcn_mfma_f32_16x16x32_bf16(a1, b, acc[1][nf], 0, 0, 0);
        }
    }

    const int r0 = (lane >> 4) * 4;
    #pragma unroll
    for (int r = 0; r < 2; ++r) {
        #pragma unroll
        for (int nf = 0; nf < 4; ++nf) {
            const int col = n0 + nf * 16 + l16;
            const float bb = bias[col];
            #pragma unroll
            for (int vv = 0; vv < 4; ++vv) {
                const int row = m0 + wv * 32 + r * 16 + r0 + vv;
                const float val = acc[r][nf][vv] + bb;
                if (C)  C [(size_t)row * 512 + col] = val;
                if (CB) CB[(size_t)row * 512 + col] = f2bf(val);
            }
        }
    }
}

__global__ __launch_bounds__(256) void proj3_kernel(
    const unsigned short* __restrict__ xb,
    const float* __restrict__ wq, const float* __restrict__ bq,
    const float* __restrict__ wk, const float* __restrict__ bk,
    const float* __restrict__ wv, const float* __restrict__ bv,
    float* __restrict__ q, float* __restrict__ k, float* __restrict__ v)
{
    const float* W; const float* b; float* C;
    if (blockIdx.z == 0)      { W = wq; b = bq; C = q; }
    else if (blockIdx.z == 1) { W = wk; b = bk; C = k; }
    else                      { W = wv; b = bv; C = v; }
    mfma_gemm_body(xb, W, b, C, nullptr);
}

__global__ __launch_bounds__(256) void outproj_kernel(
    const unsigned short* __restrict__ ctxb,
    const float* __restrict__ wo, const float* __restrict__ bo,
    float* __restrict__ out)
{
    mfma_gemm_body(ctxb, wo, bo, out, nullptr);
}

// ---------------------------------------------------------------------------
// Fused band attention: scores -> softmax -> full-row coalesced write (zeros
// outside band). QB=16 rows/block -> ~44 KB LDS -> 3 blocks/CU so compute
// hides under other blocks' store drains. Grid (256, 8).
// Partial 64-wide chunks (q0 only 16-aligned) handled by clamp + lo/hi guards.
// ---------------------------------------------------------------------------
__global__ __launch_bounds__(256) void band_attn_kernel(
    const float* __restrict__ q, const float* __restrict__ k,
    float* __restrict__ attn)
{
    __shared__ float Qs[64][20];    // Qs[d][row], 16 rows          (5.1 KB)
    __shared__ float Ks[64][68];    // Ks[d][col], 64-col chunk     (17.4 KB)
    __shared__ float P[16][336];    // band scores, local coords    (21.5 KB)
    __shared__ float rinvs[16];

    const int tid = threadIdx.x;
    const int h  = blockIdx.y;
    const int q0 = blockIdx.x * 16;
    const int w0 = q0 - 128;

    // ---- Q staging: 16 rows x 64 d; thread = (row = tid&15, 4 d's) ----
    {
        const int row = tid & 15;
        const int db  = (tid >> 4) * 4;
        float4 a = *(const float4*)&q[(size_t)(q0 + row) * 512 + h * 64 + db];
        Qs[db + 0][row] = a.x; Qs[db + 1][row] = a.y;
        Qs[db + 2][row] = a.z; Qs[db + 3][row] = a.w;
    }

    const int lr = tid >> 2;           // K stage: col 0..63
    const int ld = (tid & 3) * 16;     // K stage: 16 d's
    const int rr = tid & 15;           // score row (1 per thread)
    const int cc = (tid >> 4) * 4;     // score cols (4 per thread)

    for (int ch = 0; ch < 5; ++ch) {
        const int c0 = w0 + ch * 64;
        if (c0 + 64 <= 0 || c0 >= S) continue;   // skip only fully-outside chunks
        __syncthreads();
        {
            const int krow = min(max(c0 + lr, 0), S - 1);   // clamp partial chunks
            #pragma unroll
            for (int t = 0; t < 4; ++t) {
                float4 v4 = *(const float4*)&k[(size_t)krow * 512 + h * 64 + ld + t * 4];
                Ks[ld + t * 4 + 0][lr] = v4.x;
                Ks[ld + t * 4 + 1][lr] = v4.y;
                Ks[ld + t * 4 + 2][lr] = v4.z;
                Ks[ld + t * 4 + 3][lr] = v4.w;
            }
        }
        __syncthreads();

        float sc[4] = {};
        #pragma unroll 8
        for (int d = 0; d < 64; ++d) {
            const float qa = Qs[d][rr];
            float4 kv = *(const float4*)&Ks[d][cc];
            sc[0] = fmaf(qa, kv.x, sc[0]);
            sc[1] = fmaf(qa, kv.y, sc[1]);
            sc[2] = fmaf(qa, kv.z, sc[2]);
            sc[3] = fmaf(qa, kv.w, sc[3]);
        }

        float4 o = {sc[0] * 0.125f, sc[1] * 0.125f,
                    sc[2] * 0.125f, sc[3] * 0.125f};
        *(float4*)&P[rr][ch * 64 + cc] = o;
    }
    __syncthreads();

    // ---- per-row softmax over band (16 lanes per row) ----
    {
        const int r   = tid >> 4;
        const int l16 = tid & 15;
        const int i   = q0 + r;
        const int lo = max(i - WIN, 0) - w0;
        const int hi = min(i + WIN, S - 1) - w0;

        float m = -1e30f;
        for (int c = lo + l16; c <= hi; c += 16) m = fmaxf(m, P[r][c]);
        m = fmaxf(m, __shfl_xor(m, 1));
        m = fmaxf(m, __shfl_xor(m, 2));
        m = fmaxf(m, __shfl_xor(m, 4));
        m = fmaxf(m, __shfl_xor(m, 8));

        float sum = 0.f;
        for (int c = lo + l16; c <= hi; c += 16) {
            float e = __expf(P[r][c] - m);
            P[r][c] = e;
            sum += e;
        }
        sum += __shfl_xor(sum, 1);
        sum += __shfl_xor(sum, 2);
        sum += __shfl_xor(sum, 4);
        sum += __shfl_xor(sum, 8);
        if (l16 == 0) rinvs[r] = 1.0f / sum;
    }
    __syncthreads();

    // ---- write full rows, coalesced: 4096 floats/row, zeros outside band
    float* rowbase = attn + (size_t)h * S * S;
    #pragma unroll 1
    for (int r = 0; r < 16; ++r) {
        const int i = q0 + r;
        float* rowp = rowbase + (size_t)i * S;
        const int lo = max(i - WIN, 0) - w0;
        const int hi = min(i + WIN, S - 1) - w0;
        const float rv = rinvs[r];
        #pragma unroll
        for (int t = 0; t < 4; ++t) {
            const int c4 = (tid + t * 256) << 2;
            const int lc = c4 - w0;
            float4 o;
            if (lc >= lo && lc + 3 <= hi) {
                float4 p = *(const float4*)&P[r][lc];
                o.x = p.x * rv; o.y = p.y * rv; o.z = p.z * rv; o.w = p.w * rv;
            } else if (lc + 3 < lo || lc > hi) {
                o = make_float4(0.f, 0.f, 0.f, 0.f);
            } else {
                o.x = (lc + 0 >= lo && lc + 0 <= hi) ? P[r][lc + 0] * rv : 0.f;
                o.y = (lc + 1 >= lo && lc + 1 <= hi) ? P[r][lc + 1] * rv : 0.f;
                o.z = (lc + 2 >= lo && lc + 2 <= hi) ? P[r][lc + 2] * rv : 0.f;
                o.w = (lc + 3 >= lo && lc + 3 <= hi) ? P[r][lc + 3] * rv : 0.f;
            }
            *(float4*)&rowp[c4] = o;
        }
    }
}

// ---------------------------------------------------------------------------
// PV via MFMA: ctx[64][64] = P[64][320] x V[320][64] per (q-block, head).
// P read from attn rows (fp32 -> bf16), V transposed into LDS as bf16.
// q0 is 64-aligned here, so chunks are never partial.
// ---------------------------------------------------------------------------
__global__ __launch_bounds__(256) void band_pv_kernel(
    const float* __restrict__ attn, const float* __restrict__ v,
    unsigned short* __restrict__ ctxb)
{
    __shared__ unsigned short Pb [64][328];   // Pb[row][local col]
    __shared__ unsigned short VsT[64][328];   // VsT[d][local col]
    const int tid = threadIdx.x;
    const int h  = blockIdx.y;
    const int q0 = blockIdx.x * 64;
    const int w0 = q0 - 128;

    const int lr = tid >> 2;           // 0..63
    const int ld = (tid & 3) * 16;     // 0,16,32,48
    const float* aptr = attn + (size_t)h * S * S;

    for (int ch = 0; ch < 5; ++ch) {
        const int c0 = w0 + ch * 64;
        if (c0 >= 0 && c0 < S) {
            #pragma unroll
            for (int t = 0; t < 4; ++t) {
                float4 p4 = *(const float4*)&aptr[(size_t)(q0 + lr) * S + c0 + ld + t * 4];
                ushort4 o = {f2bf(p4.x), f2bf(p4.y), f2bf(p4.z), f2bf(p4.w)};
                *(ushort4*)&Pb[lr][ch * 64 + ld + t * 4] = o;
                float4 v4 = *(const float4*)&v[(size_t)(c0 + lr) * 512 + h * 64 + ld + t * 4];
                VsT[ld + t * 4 + 0][ch * 64 + lr] = f2bf(v4.x);
                VsT[ld + t * 4 + 1][ch * 64 + lr] = f2bf(v4.y);
                VsT[ld + t * 4 + 2][ch * 64 + lr] = f2bf(v4.z);
                VsT[ld + t * 4 + 3][ch * 64 + lr] = f2bf(v4.w);
            }
        } else {
            #pragma unroll
            for (int t = 0; t < 4; ++t) {
                ushort4 z4 = {0, 0, 0, 0};
                *(ushort4*)&Pb[lr][ch * 64 + ld + t * 4] = z4;
                VsT[ld + t * 4 + 0][ch * 64 + lr] = 0;
                VsT[ld + t * 4 + 1][ch * 64 + lr] = 0;
                VsT[ld + t * 4 + 2][ch * 64 + lr] = 0;
                VsT[ld + t * 4 + 3][ch * 64 + lr] = 0;
            }
        }
    }
    __syncthreads();

    const int wv   = tid >> 6;
    const int lane = tid & 63;
    const int l16  = lane & 15;
    const int klo  = (lane >> 4) * 8;

    f32x4 acc[4];
    #pragma unroll
    for (int nf = 0; nf < 4; ++nf) acc[nf] = (f32x4){0.f, 0.f, 0.f, 0.f};

    #pragma unroll
    for (int ks = 0; ks < 10; ++ks) {
        bf16x8 a = *(const bf16x8*)&Pb[wv * 16 + l16][ks * 32 + klo];
        #pragma unroll
        for (int nf = 0; nf < 4; ++nf) {
            bf16x8 b = *(const bf16x8*)&VsT[nf * 16 + l16][ks * 32 + klo];
            acc[nf] = __builtin_amdgcn_mfma_f32_16x16x32_bf16(a, b, acc[nf], 0, 0, 0);
        }
    }

    const int r0 = (lane >> 4) * 4;
    #pragma unroll
    for (int nf = 0; nf < 4; ++nf) {
        #pragma unroll
        for (int vv = 0; vv < 4; ++vv) {
            const int row = q0 + wv * 16 + r0 + vv;
            ctxb[(size_t)row * 512 + h * 64 + nf * 16 + l16] = f2bf(acc[nf][vv]);
        }
    }
}

// ---------------------------------------------------------------------------
extern "C" void kernel_launch(void* const* d_in, const int* in_sizes, int n_in,
                              void* d_out, int out_size, void* d_ws, size_t ws_size,
                              hipStream_t stream)
{
    (void)in_sizes; (void)n_in; (void)out_size; (void)ws_size;
    const float* x  = (const float*)d_in[0];
    const float* wq = (const float*)d_in[1];
    const float* bq = (const float*)d_in[2];
    const float* wk = (const float*)d_in[3];
    const float* bk = (const float*)d_in[4];
    const float* wv = (const float*)d_in[5];
    const float* bv = (const float*)d_in[6];
    const float* wo = (const float*)d_in[7];
    const float* bo = (const float*)d_in[8];

    float* out  = (float*)d_out;                       // (S, D)
    float* attn = out + (size_t)S * D;                 // (H, S, S)

    float* q = (float*)d_ws;                           // 8 MB each
    float* k = q + (size_t)S * D;
    float* v = k + (size_t)S * D;
    unsigned short* xb   = (unsigned short*)(v + (size_t)S * D);  // 4 MB
    unsigned short* ctxb = xb + (size_t)S * D;                    // 4 MB

    conv_bf16_kernel<<<(S * D) / (256 * 8), 256, 0, stream>>>(x, xb, S * D);
    proj3_kernel<<<dim3(32, 8, 3), 256, 0, stream>>>(xb, wq, bq, wk, bk, wv, bv, q, k, v);
    band_attn_kernel<<<dim3(256, 8), 256, 0, stream>>>(q, k, attn);
    band_pv_kernel<<<dim3(64, 8), 256, 0, stream>>>(attn, v, ctxb);
    outproj_kernel<<<dim3(32, 8), 256, 0, stream>>>(ctxb, wo, bo, out);
}

// Round 10
// 159.341 us; speedup vs baseline: 1.4341x; 1.0871x over previous
//
#include <hip/hip_runtime.h>
#include <hip/hip_bf16.h>
#include <math.h>

#define S 4096
#define D 512
#define H 8
#define DK 64
#define WIN 128

typedef __attribute__((ext_vector_type(8))) short bf16x8;
typedef __attribute__((ext_vector_type(4))) float f32x4;

__device__ __forceinline__ unsigned short f2bf(float f) {
    __hip_bfloat16 h = __float2bfloat16(f);
    return *(unsigned short*)&h;
}

// ---------------------------------------------------------------------------
// fp32 -> bf16 conversion (x). 8 elems/thread.
// ---------------------------------------------------------------------------
__global__ __launch_bounds__(256) void conv_bf16_kernel(
    const float* __restrict__ in, unsigned short* __restrict__ out, int n)
{
    const int i = (blockIdx.x * 256 + threadIdx.x) * 8;
    if (i >= n) return;
    float4 a = *(const float4*)&in[i];
    float4 b = *(const float4*)&in[i + 4];
    ushort4 o0 = {f2bf(a.x), f2bf(a.y), f2bf(a.z), f2bf(a.w)};
    ushort4 o1 = {f2bf(b.x), f2bf(b.y), f2bf(b.z), f2bf(b.w)};
    *(ushort4*)&out[i]     = o0;
    *(ushort4*)&out[i + 4] = o1;
}

// ---------------------------------------------------------------------------
// MFMA GEMM: C[m][n] = sum_e A[m][e]*W[n][e] + bias[n]
// C (fp32) and/or CB (bf16) outputs.
// ---------------------------------------------------------------------------
__device__ __forceinline__ void mfma_gemm_body(
    const unsigned short* __restrict__ A,
    const float* __restrict__ W,
    const float* __restrict__ bias,
    float* __restrict__ C,
    unsigned short* __restrict__ CB)
{
    __shared__ unsigned short Bs[64][520];

    const int tid  = threadIdx.x;
    const int m0   = blockIdx.x * 128;
    const int n0   = blockIdx.y * 64;
    const int wv   = tid >> 6;
    const int lane = tid & 63;
    const int l16  = lane & 15;
    const int klo  = (lane >> 4) * 8;

    #pragma unroll
    for (int it = 0; it < 16; ++it) {
        const int c   = tid + it * 256;
        const int row = c >> 6;
        const int kc  = (c & 63) * 8;
        const float* src = &W[(size_t)(n0 + row) * 512 + kc];
        float4 a = *(const float4*)&src[0];
        float4 b = *(const float4*)&src[4];
        ushort4 o0 = {f2bf(a.x), f2bf(a.y), f2bf(a.z), f2bf(a.w)};
        ushort4 o1 = {f2bf(b.x), f2bf(b.y), f2bf(b.z), f2bf(b.w)};
        *(ushort4*)&Bs[row][kc]     = o0;
        *(ushort4*)&Bs[row][kc + 4] = o1;
    }
    __syncthreads();

    const unsigned short* arow0 = &A[(size_t)(m0 + wv * 32 + l16) * 512 + klo];
    const unsigned short* arow1 = arow0 + 16 * 512;

    f32x4 acc[2][4];
    #pragma unroll
    for (int r = 0; r < 2; ++r)
        #pragma unroll
        for (int nf = 0; nf < 4; ++nf)
            acc[r][nf] = (f32x4){0.f, 0.f, 0.f, 0.f};

    #pragma unroll 4
    for (int kb = 0; kb < 512; kb += 32) {
        bf16x8 a0 = *(const bf16x8*)&arow0[kb];
        bf16x8 a1 = *(const bf16x8*)&arow1[kb];
        #pragma unroll
        for (int nf = 0; nf < 4; ++nf) {
            bf16x8 b = *(const bf16x8*)&Bs[nf * 16 + l16][kb + klo];
            acc[0][nf] = __builtin_amdgcn_mfma_f32_16x16x32_bf16(a0, b, acc[0][nf], 0, 0, 0);
            acc[1][nf] = __builtin_amdgcn_mfma_f32_16x16x32_bf16(a1, b, acc[1][nf], 0, 0, 0);
        }
    }

    const int r0 = (lane >> 4) * 4;
    #pragma unroll
    for (int r = 0; r < 2; ++r) {
        #pragma unroll
        for (int nf = 0; nf < 4; ++nf) {
            const int col = n0 + nf * 16 + l16;
            const float bb = bias[col];
            #pragma unroll
            for (int vv = 0; vv < 4; ++vv) {
                const int row = m0 + wv * 32 + r * 16 + r0 + vv;
                const float val = acc[r][nf][vv] + bb;
                if (C)  C [(size_t)row * 512 + col] = val;
                if (CB) CB[(size_t)row * 512 + col] = f2bf(val);
            }
        }
    }
}

__global__ __launch_bounds__(256) void proj3_kernel(
    const unsigned short* __restrict__ xb,
    const float* __restrict__ wq, const float* __restrict__ bq,
    const float* __restrict__ wk, const float* __restrict__ bk,
    const float* __restrict__ wv, const float* __restrict__ bv,
    unsigned short* __restrict__ qb, unsigned short* __restrict__ kb,
    unsigned short* __restrict__ vb)
{
    const float* W; const float* b; unsigned short* CB;
    if (blockIdx.z == 0)      { W = wq; b = bq; CB = qb; }
    else if (blockIdx.z == 1) { W = wk; b = bk; CB = kb; }
    else                      { W = wv; b = bv; CB = vb; }
    mfma_gemm_body(xb, W, b, nullptr, CB);
}

__global__ __launch_bounds__(256) void outproj_kernel(
    const unsigned short* __restrict__ ctxb,
    const float* __restrict__ wo, const float* __restrict__ bo,
    float* __restrict__ out)
{
    mfma_gemm_body(ctxb, wo, bo, out, nullptr);
}

// ---------------------------------------------------------------------------
// Fused band attention: MFMA QK^T -> softmax -> full-row coalesced write
// (zeros outside band). QB=16 rows/block, bf16 Q/K staging, ~33 KB LDS ->
// 4 blocks/CU. Grid (256, 8). Partial 64-wide chunks handled by clamp.
// ---------------------------------------------------------------------------
__global__ __launch_bounds__(256) void band_attn_kernel(
    const unsigned short* __restrict__ qb, const unsigned short* __restrict__ kb,
    float* __restrict__ attn)
{
    __shared__ __align__(16) unsigned short Qs[16][72];  // Qs[row][d]  (2.3 KB)
    __shared__ __align__(16) unsigned short Kb[64][72];  // Kb[col][d]  (9.2 KB)
    __shared__ float P[16][336];                         // scores      (21.5 KB)
    __shared__ float rinvs[16];

    const int tid = threadIdx.x;
    const int h  = blockIdx.y;
    const int q0 = blockIdx.x * 16;
    const int w0 = q0 - 128;

    const int wv   = tid >> 6;
    const int lane = tid & 63;
    const int l16  = lane & 15;
    const int klo  = (lane >> 4) * 8;
    const int r0   = (lane >> 4) * 4;

    // ---- Q staging: 16 rows x 64 d bf16; thread = (row = tid>>4, 4 d's) ----
    {
        const int row = tid >> 4;
        const int db  = (tid & 15) * 4;
        *(ushort4*)&Qs[row][db] =
            *(const ushort4*)&qb[(size_t)(q0 + row) * 512 + h * 64 + db];
    }

    const int lr = tid >> 2;           // K stage: col 0..63
    const int ld = (tid & 3) * 16;     // K stage: 16 d's

    for (int ch = 0; ch < 5; ++ch) {
        const int c0 = w0 + ch * 64;
        if (c0 + 64 <= 0 || c0 >= S) continue;   // skip fully-outside chunks
        __syncthreads();
        {
            const int krow = min(max(c0 + lr, 0), S - 1);   // clamp partials
            const unsigned short* src = &kb[(size_t)krow * 512 + h * 64 + ld];
            *(bf16x8*)&Kb[lr][ld]     = *(const bf16x8*)&src[0];
            *(bf16x8*)&Kb[lr][ld + 8] = *(const bf16x8*)&src[8];
        }
        __syncthreads();

        // wave wv computes cols [wv*16, wv*16+16) of this 64-col chunk
        f32x4 acc = (f32x4){0.f, 0.f, 0.f, 0.f};
        #pragma unroll
        for (int kk = 0; kk < 64; kk += 32) {
            bf16x8 a = *(const bf16x8*)&Qs[l16][kk + klo];
            bf16x8 b = *(const bf16x8*)&Kb[wv * 16 + l16][kk + klo];
            acc = __builtin_amdgcn_mfma_f32_16x16x32_bf16(a, b, acc, 0, 0, 0);
        }
        #pragma unroll
        for (int vv = 0; vv < 4; ++vv)
            P[r0 + vv][ch * 64 + wv * 16 + l16] = acc[vv] * 0.125f;
    }
    __syncthreads();

    // ---- per-row softmax over band (16 lanes per row) ----
    {
        const int r   = tid >> 4;
        const int lx  = tid & 15;
        const int i   = q0 + r;
        const int lo = max(i - WIN, 0) - w0;
        const int hi = min(i + WIN, S - 1) - w0;

        float m = -1e30f;
        for (int c = lo + lx; c <= hi; c += 16) m = fmaxf(m, P[r][c]);
        m = fmaxf(m, __shfl_xor(m, 1));
        m = fmaxf(m, __shfl_xor(m, 2));
        m = fmaxf(m, __shfl_xor(m, 4));
        m = fmaxf(m, __shfl_xor(m, 8));

        float sum = 0.f;
        for (int c = lo + lx; c <= hi; c += 16) {
            float e = __expf(P[r][c] - m);
            P[r][c] = e;
            sum += e;
        }
        sum += __shfl_xor(sum, 1);
        sum += __shfl_xor(sum, 2);
        sum += __shfl_xor(sum, 4);
        sum += __shfl_xor(sum, 8);
        if (lx == 0) rinvs[r] = 1.0f / sum;
    }
    __syncthreads();

    // ---- write full rows, coalesced: 4096 floats/row, zeros outside band
    float* rowbase = attn + (size_t)h * S * S;
    #pragma unroll 1
    for (int r = 0; r < 16; ++r) {
        const int i = q0 + r;
        float* rowp = rowbase + (size_t)i * S;
        const int lo = max(i - WIN, 0) - w0;
        const int hi = min(i + WIN, S - 1) - w0;
        const float rv = rinvs[r];
        #pragma unroll
        for (int t = 0; t < 4; ++t) {
            const int c4 = (tid + t * 256) << 2;
            const int lc = c4 - w0;
            float4 o;
            if (lc >= lo && lc + 3 <= hi) {
                float4 p = *(const float4*)&P[r][lc];
                o.x = p.x * rv; o.y = p.y * rv; o.z = p.z * rv; o.w = p.w * rv;
            } else if (lc + 3 < lo || lc > hi) {
                o = make_float4(0.f, 0.f, 0.f, 0.f);
            } else {
                o.x = (lc + 0 >= lo && lc + 0 <= hi) ? P[r][lc + 0] * rv : 0.f;
                o.y = (lc + 1 >= lo && lc + 1 <= hi) ? P[r][lc + 1] * rv : 0.f;
                o.z = (lc + 2 >= lo && lc + 2 <= hi) ? P[r][lc + 2] * rv : 0.f;
                o.w = (lc + 3 >= lo && lc + 3 <= hi) ? P[r][lc + 3] * rv : 0.f;
            }
            *(float4*)&rowp[c4] = o;
        }
    }
}

// ---------------------------------------------------------------------------
// PV via MFMA: ctx[64][64] = P[64][320] x V[320][64] per (q-block, head).
// P read from attn rows (fp32 -> bf16), V (already bf16) transposed into LDS.
// q0 is 64-aligned here, so chunks are never partial.
// ---------------------------------------------------------------------------
__global__ __launch_bounds__(256) void band_pv_kernel(
    const float* __restrict__ attn, const unsigned short* __restrict__ vb,
    unsigned short* __restrict__ ctxb)
{
    __shared__ unsigned short Pb [64][328];   // Pb[row][local col]
    __shared__ unsigned short VsT[64][328];   // VsT[d][local col]
    const int tid = threadIdx.x;
    const int h  = blockIdx.y;
    const int q0 = blockIdx.x * 64;
    const int w0 = q0 - 128;

    const int lr = tid >> 2;           // 0..63
    const int ld = (tid & 3) * 16;     // 0,16,32,48
    const float* aptr = attn + (size_t)h * S * S;

    for (int ch = 0; ch < 5; ++ch) {
        const int c0 = w0 + ch * 64;
        if (c0 >= 0 && c0 < S) {
            #pragma unroll
            for (int t = 0; t < 4; ++t) {
                float4 p4 = *(const float4*)&aptr[(size_t)(q0 + lr) * S + c0 + ld + t * 4];
                ushort4 o = {f2bf(p4.x), f2bf(p4.y), f2bf(p4.z), f2bf(p4.w)};
                *(ushort4*)&Pb[lr][ch * 64 + ld + t * 4] = o;
                ushort4 v4 = *(const ushort4*)&vb[(size_t)(c0 + lr) * 512 + h * 64 + ld + t * 4];
                VsT[ld + t * 4 + 0][ch * 64 + lr] = v4.x;
                VsT[ld + t * 4 + 1][ch * 64 + lr] = v4.y;
                VsT[ld + t * 4 + 2][ch * 64 + lr] = v4.z;
                VsT[ld + t * 4 + 3][ch * 64 + lr] = v4.w;
            }
        } else {
            #pragma unroll
            for (int t = 0; t < 4; ++t) {
                ushort4 z4 = {0, 0, 0, 0};
                *(ushort4*)&Pb[lr][ch * 64 + ld + t * 4] = z4;
                VsT[ld + t * 4 + 0][ch * 64 + lr] = 0;
                VsT[ld + t * 4 + 1][ch * 64 + lr] = 0;
                VsT[ld + t * 4 + 2][ch * 64 + lr] = 0;
                VsT[ld + t * 4 + 3][ch * 64 + lr] = 0;
            }
        }
    }
    __syncthreads();

    const int wv   = tid >> 6;
    const int lane = tid & 63;
    const int l16  = lane & 15;
    const int klo  = (lane >> 4) * 8;

    f32x4 acc[4];
    #pragma unroll
    for (int nf = 0; nf < 4; ++nf) acc[nf] = (f32x4){0.f, 0.f, 0.f, 0.f};

    #pragma unroll
    for (int ks = 0; ks < 10; ++ks) {
        bf16x8 a = *(const bf16x8*)&Pb[wv * 16 + l16][ks * 32 + klo];
        #pragma unroll
        for (int nf = 0; nf < 4; ++nf) {
            bf16x8 b = *(const bf16x8*)&VsT[nf * 16 + l16][ks * 32 + klo];
            acc[nf] = __builtin_amdgcn_mfma_f32_16x16x32_bf16(a, b, acc[nf], 0, 0, 0);
        }
    }

    const int r0 = (lane >> 4) * 4;
    #pragma unroll
    for (int nf = 0; nf < 4; ++nf) {
        #pragma unroll
        for (int vv = 0; vv < 4; ++vv) {
            const int row = q0 + wv * 16 + r0 + vv;
            ctxb[(size_t)row * 512 + h * 64 + nf * 16 + l16] = f2bf(acc[nf][vv]);
        }
    }
}

// ---------------------------------------------------------------------------
extern "C" void kernel_launch(void* const* d_in, const int* in_sizes, int n_in,
                              void* d_out, int out_size, void* d_ws, size_t ws_size,
                              hipStream_t stream)
{
    (void)in_sizes; (void)n_in; (void)out_size; (void)ws_size;
    const float* x  = (const float*)d_in[0];
    const float* wq = (const float*)d_in[1];
    const float* bq = (const float*)d_in[2];
    const float* wk = (const float*)d_in[3];
    const float* bk = (const float*)d_in[4];
    const float* wv = (const float*)d_in[5];
    const float* bv = (const float*)d_in[6];
    const float* wo = (const float*)d_in[7];
    const float* bo = (const float*)d_in[8];

    float* out  = (float*)d_out;                       // (S, D)
    float* attn = out + (size_t)S * D;                 // (H, S, S)

    unsigned short* xb   = (unsigned short*)d_ws;                 // 4 MB each
    unsigned short* qb   = xb   + (size_t)S * D;
    unsigned short* kb   = qb   + (size_t)S * D;
    unsigned short* vb   = kb   + (size_t)S * D;
    unsigned short* ctxb = vb   + (size_t)S * D;

    conv_bf16_kernel<<<(S * D) / (256 * 8), 256, 0, stream>>>(x, xb, S * D);
    proj3_kernel<<<dim3(32, 8, 3), 256, 0, stream>>>(xb, wq, bq, wk, bk, wv, bv, qb, kb, vb);
    band_attn_kernel<<<dim3(256, 8), 256, 0, stream>>>(qb, kb, attn);
    band_pv_kernel<<<dim3(64, 8), 256, 0, stream>>>(attn, vb, ctxb);
    outproj_kernel<<<dim3(32, 8), 256, 0, stream>>>(ctxb, wo, bo, out);
}

// Round 11
// 153.309 us; speedup vs baseline: 1.4906x; 1.0393x over previous
//
#include <hip/hip_runtime.h>
#include <hip/hip_bf16.h>
#include <math.h>

#define S 4096
#define D 512
#define H 8
#define DK 64
#define WIN 128

typedef __attribute__((ext_vector_type(8))) short bf16x8;
typedef __attribute__((ext_vector_type(4))) float f32x4;

__device__ __forceinline__ unsigned short f2bf(float f) {
    __hip_bfloat16 h = __float2bfloat16(f);
    return *(unsigned short*)&h;
}

// ---------------------------------------------------------------------------
// fp32 -> bf16 conversion (x). 8 elems/thread.
// ---------------------------------------------------------------------------
__global__ __launch_bounds__(256) void conv_bf16_kernel(
    const float* __restrict__ in, unsigned short* __restrict__ out, int n)
{
    const int i = (blockIdx.x * 256 + threadIdx.x) * 8;
    if (i >= n) return;
    float4 a = *(const float4*)&in[i];
    float4 b = *(const float4*)&in[i + 4];
    ushort4 o0 = {f2bf(a.x), f2bf(a.y), f2bf(a.z), f2bf(a.w)};
    ushort4 o1 = {f2bf(b.x), f2bf(b.y), f2bf(b.z), f2bf(b.w)};
    *(ushort4*)&out[i]     = o0;
    *(ushort4*)&out[i + 4] = o1;
}

// ---------------------------------------------------------------------------
// MFMA GEMM: C[m][n] = sum_e A[m][e]*W[n][e] + bias[n]
// C (fp32) and/or CB (bf16) outputs.
// ---------------------------------------------------------------------------
__device__ __forceinline__ void mfma_gemm_body(
    const unsigned short* __restrict__ A,
    const float* __restrict__ W,
    const float* __restrict__ bias,
    float* __restrict__ C,
    unsigned short* __restrict__ CB)
{
    __shared__ unsigned short Bs[64][520];

    const int tid  = threadIdx.x;
    const int m0   = blockIdx.x * 128;
    const int n0   = blockIdx.y * 64;
    const int wv   = tid >> 6;
    const int lane = tid & 63;
    const int l16  = lane & 15;
    const int klo  = (lane >> 4) * 8;

    #pragma unroll
    for (int it = 0; it < 16; ++it) {
        const int c   = tid + it * 256;
        const int row = c >> 6;
        const int kc  = (c & 63) * 8;
        const float* src = &W[(size_t)(n0 + row) * 512 + kc];
        float4 a = *(const float4*)&src[0];
        float4 b = *(const float4*)&src[4];
        ushort4 o0 = {f2bf(a.x), f2bf(a.y), f2bf(a.z), f2bf(a.w)};
        ushort4 o1 = {f2bf(b.x), f2bf(b.y), f2bf(b.z), f2bf(b.w)};
        *(ushort4*)&Bs[row][kc]     = o0;
        *(ushort4*)&Bs[row][kc + 4] = o1;
    }
    __syncthreads();

    const unsigned short* arow0 = &A[(size_t)(m0 + wv * 32 + l16) * 512 + klo];
    const unsigned short* arow1 = arow0 + 16 * 512;

    f32x4 acc[2][4];
    #pragma unroll
    for (int r = 0; r < 2; ++r)
        #pragma unroll
        for (int nf = 0; nf < 4; ++nf)
            acc[r][nf] = (f32x4){0.f, 0.f, 0.f, 0.f};

    #pragma unroll 4
    for (int kb = 0; kb < 512; kb += 32) {
        bf16x8 a0 = *(const bf16x8*)&arow0[kb];
        bf16x8 a1 = *(const bf16x8*)&arow1[kb];
        #pragma unroll
        for (int nf = 0; nf < 4; ++nf) {
            bf16x8 b = *(const bf16x8*)&Bs[nf * 16 + l16][kb + klo];
            acc[0][nf] = __builtin_amdgcn_mfma_f32_16x16x32_bf16(a0, b, acc[0][nf], 0, 0, 0);
            acc[1][nf] = __builtin_amdgcn_mfma_f32_16x16x32_bf16(a1, b, acc[1][nf], 0, 0, 0);
        }
    }

    const int r0 = (lane >> 4) * 4;
    #pragma unroll
    for (int r = 0; r < 2; ++r) {
        #pragma unroll
        for (int nf = 0; nf < 4; ++nf) {
            const int col = n0 + nf * 16 + l16;
            const float bb = bias[col];
            #pragma unroll
            for (int vv = 0; vv < 4; ++vv) {
                const int row = m0 + wv * 32 + r * 16 + r0 + vv;
                const float val = acc[r][nf][vv] + bb;
                if (C)  C [(size_t)row * 512 + col] = val;
                if (CB) CB[(size_t)row * 512 + col] = f2bf(val);
            }
        }
    }
}

__global__ __launch_bounds__(256) void proj3_kernel(
    const unsigned short* __restrict__ xb,
    const float* __restrict__ wq, const float* __restrict__ bq,
    const float* __restrict__ wk, const float* __restrict__ bk,
    const float* __restrict__ wv, const float* __restrict__ bv,
    unsigned short* __restrict__ qb, unsigned short* __restrict__ kb,
    unsigned short* __restrict__ vb)
{
    const float* W; const float* b; unsigned short* CB;
    if (blockIdx.z == 0)      { W = wq; b = bq; CB = qb; }
    else if (blockIdx.z == 1) { W = wk; b = bk; CB = kb; }
    else                      { W = wv; b = bv; CB = vb; }
    mfma_gemm_body(xb, W, b, nullptr, CB);
}

__global__ __launch_bounds__(256) void outproj_kernel(
    const unsigned short* __restrict__ ctxb,
    const float* __restrict__ wo, const float* __restrict__ bo,
    float* __restrict__ out)
{
    mfma_gemm_body(ctxb, wo, bo, out, nullptr);
}

// ---------------------------------------------------------------------------
// Fully fused band attention: MFMA QK^T -> softmax (P zeroed out-of-band) ->
// MFMA PV (V reuses the K LDS buffer) -> ctx write -> full-row attn write.
// QB=16 rows/block, ~33 KB LDS -> 4 blocks/CU. Grid (256, 8).
// Partial 64-wide chunks handled by clamp + zeroed P.
// ---------------------------------------------------------------------------
__global__ __launch_bounds__(256) void band_attn_kernel(
    const unsigned short* __restrict__ qb, const unsigned short* __restrict__ kb,
    const unsigned short* __restrict__ vb,
    float* __restrict__ attn, unsigned short* __restrict__ ctxb)
{
    __shared__ __align__(16) unsigned short Qs[16][72];  // Qs[row][d]   (2.3 KB)
    __shared__ __align__(16) unsigned short KV[64][72];  // K:[col][d] / V:[d][col]
    __shared__ float P[16][336];                         // exp-scores   (21.5 KB)
    __shared__ float rinvs[16];

    const int tid = threadIdx.x;
    const int h  = blockIdx.y;
    const int q0 = blockIdx.x * 16;
    const int w0 = q0 - 128;

    const int wv   = tid >> 6;
    const int lane = tid & 63;
    const int l16  = lane & 15;
    const int klo  = (lane >> 4) * 8;
    const int r0   = (lane >> 4) * 4;

    // ---- Q staging: 16 rows x 64 d bf16 ----
    {
        const int row = tid >> 4;
        const int db  = (tid & 15) * 4;
        *(ushort4*)&Qs[row][db] =
            *(const ushort4*)&qb[(size_t)(q0 + row) * 512 + h * 64 + db];
    }

    const int lr = tid >> 2;           // stage: col/row 0..63
    const int ld = (tid & 3) * 16;     // stage: 16 d's

    // ================= QK^T phase =================
    for (int ch = 0; ch < 5; ++ch) {
        const int c0 = w0 + ch * 64;
        if (c0 + 64 <= 0 || c0 >= S) continue;   // skip fully-outside chunks
        __syncthreads();
        {
            const int krow = min(max(c0 + lr, 0), S - 1);   // clamp partials
            const unsigned short* src = &kb[(size_t)krow * 512 + h * 64 + ld];
            *(bf16x8*)&KV[lr][ld]     = *(const bf16x8*)&src[0];
            *(bf16x8*)&KV[lr][ld + 8] = *(const bf16x8*)&src[8];
        }
        __syncthreads();

        f32x4 acc = (f32x4){0.f, 0.f, 0.f, 0.f};
        #pragma unroll
        for (int kk = 0; kk < 64; kk += 32) {
            bf16x8 a = *(const bf16x8*)&Qs[l16][kk + klo];
            bf16x8 b = *(const bf16x8*)&KV[wv * 16 + l16][kk + klo];
            acc = __builtin_amdgcn_mfma_f32_16x16x32_bf16(a, b, acc, 0, 0, 0);
        }
        #pragma unroll
        for (int vv = 0; vv < 4; ++vv)
            P[r0 + vv][ch * 64 + wv * 16 + l16] = acc[vv] * 0.125f;
    }
    __syncthreads();

    // ---- softmax: exp in band, ZERO outside band (cols [0,320)) ----
    {
        const int r   = tid >> 4;
        const int lx  = tid & 15;
        const int i   = q0 + r;
        const int lo = max(i - WIN, 0) - w0;
        const int hi = min(i + WIN, S - 1) - w0;

        float m = -1e30f;
        for (int c = lo + lx; c <= hi; c += 16) m = fmaxf(m, P[r][c]);
        m = fmaxf(m, __shfl_xor(m, 1));
        m = fmaxf(m, __shfl_xor(m, 2));
        m = fmaxf(m, __shfl_xor(m, 4));
        m = fmaxf(m, __shfl_xor(m, 8));

        float sum = 0.f;
        for (int c = lx; c < 320; c += 16) {
            float e = 0.f;
            if (c >= lo && c <= hi) {
                e = __expf(P[r][c] - m);
                sum += e;
            }
            P[r][c] = e;
        }
        sum += __shfl_xor(sum, 1);
        sum += __shfl_xor(sum, 2);
        sum += __shfl_xor(sum, 4);
        sum += __shfl_xor(sum, 8);
        if (lx == 0) rinvs[r] = 1.0f / sum;
    }

    // ================= PV phase (V reuses KV buffer) =================
    f32x4 pacc = (f32x4){0.f, 0.f, 0.f, 0.f};
    for (int ch = 0; ch < 5; ++ch) {
        const int c0 = w0 + ch * 64;
        if (c0 + 64 <= 0 || c0 >= S) continue;
        __syncthreads();
        {
            const int vrow = min(max(c0 + lr, 0), S - 1);   // clamp (P=0 there)
            ushort4 v0 = *(const ushort4*)&vb[(size_t)vrow * 512 + h * 64 + ld];
            ushort4 v1 = *(const ushort4*)&vb[(size_t)vrow * 512 + h * 64 + ld + 4];
            ushort4 v2 = *(const ushort4*)&vb[(size_t)vrow * 512 + h * 64 + ld + 8];
            ushort4 v3 = *(const ushort4*)&vb[(size_t)vrow * 512 + h * 64 + ld + 12];
            KV[ld +  0][lr] = v0.x; KV[ld +  1][lr] = v0.y;
            KV[ld +  2][lr] = v0.z; KV[ld +  3][lr] = v0.w;
            KV[ld +  4][lr] = v1.x; KV[ld +  5][lr] = v1.y;
            KV[ld +  6][lr] = v1.z; KV[ld +  7][lr] = v1.w;
            KV[ld +  8][lr] = v2.x; KV[ld +  9][lr] = v2.y;
            KV[ld + 10][lr] = v2.z; KV[ld + 11][lr] = v2.w;
            KV[ld + 12][lr] = v3.x; KV[ld + 13][lr] = v3.y;
            KV[ld + 14][lr] = v3.z; KV[ld + 15][lr] = v3.w;
        }
        __syncthreads();

        #pragma unroll
        for (int kk = 0; kk < 64; kk += 32) {
            unsigned short abuf[8];
            #pragma unroll
            for (int e = 0; e < 8; ++e)
                abuf[e] = f2bf(P[l16][ch * 64 + kk + klo + e]);
            bf16x8 a = *(const bf16x8*)abuf;
            bf16x8 b = *(const bf16x8*)&KV[wv * 16 + l16][kk + klo];
            pacc = __builtin_amdgcn_mfma_f32_16x16x32_bf16(a, b, pacc, 0, 0, 0);
        }
    }

    // ---- ctx write: row = q0 + r0+vv, col = h*64 + wv*16 + l16 ----
    #pragma unroll
    for (int vv = 0; vv < 4; ++vv) {
        const int row = q0 + r0 + vv;
        ctxb[(size_t)row * 512 + h * 64 + wv * 16 + l16] =
            f2bf(pacc[vv] * rinvs[r0 + vv]);
    }

    // ---- write full attn rows, coalesced; zeros outside band ----
    float* rowbase = attn + (size_t)h * S * S;
    #pragma unroll 1
    for (int r = 0; r < 16; ++r) {
        const int i = q0 + r;
        float* rowp = rowbase + (size_t)i * S;
        const int lo = max(i - WIN, 0) - w0;
        const int hi = min(i + WIN, S - 1) - w0;
        const float rv = rinvs[r];
        #pragma unroll
        for (int t = 0; t < 4; ++t) {
            const int c4 = (tid + t * 256) << 2;
            const int lc = c4 - w0;
            float4 o;
            if (lc >= lo && lc + 3 <= hi) {
                float4 p = *(const float4*)&P[r][lc];
                o.x = p.x * rv; o.y = p.y * rv; o.z = p.z * rv; o.w = p.w * rv;
            } else if (lc + 3 < lo || lc > hi) {
                o = make_float4(0.f, 0.f, 0.f, 0.f);
            } else {
                o.x = (lc + 0 >= lo && lc + 0 <= hi) ? P[r][lc + 0] * rv : 0.f;
                o.y = (lc + 1 >= lo && lc + 1 <= hi) ? P[r][lc + 1] * rv : 0.f;
                o.z = (lc + 2 >= lo && lc + 2 <= hi) ? P[r][lc + 2] * rv : 0.f;
                o.w = (lc + 3 >= lo && lc + 3 <= hi) ? P[r][lc + 3] * rv : 0.f;
            }
            *(float4*)&rowp[c4] = o;
        }
    }
}

// ---------------------------------------------------------------------------
extern "C" void kernel_launch(void* const* d_in, const int* in_sizes, int n_in,
                              void* d_out, int out_size, void* d_ws, size_t ws_size,
                              hipStream_t stream)
{
    (void)in_sizes; (void)n_in; (void)out_size; (void)ws_size;
    const float* x  = (const float*)d_in[0];
    const float* wq = (const float*)d_in[1];
    const float* bq = (const float*)d_in[2];
    const float* wk = (const float*)d_in[3];
    const float* bk = (const float*)d_in[4];
    const float* wv = (const float*)d_in[5];
    const float* bv = (const float*)d_in[6];
    const float* wo = (const float*)d_in[7];
    const float* bo = (const float*)d_in[8];

    float* out  = (float*)d_out;                       // (S, D)
    float* attn = out + (size_t)S * D;                 // (H, S, S)

    unsigned short* xb   = (unsigned short*)d_ws;                 // 4 MB each
    unsigned short* qb   = xb   + (size_t)S * D;
    unsigned short* kb   = qb   + (size_t)S * D;
    unsigned short* vb   = kb   + (size_t)S * D;
    unsigned short* ctxb = vb   + (size_t)S * D;

    conv_bf16_kernel<<<(S * D) / (256 * 8), 256, 0, stream>>>(x, xb, S * D);
    proj3_kernel<<<dim3(32, 8, 3), 256, 0, stream>>>(xb, wq, bq, wk, bk, wv, bv, qb, kb, vb);
    band_attn_kernel<<<dim3(256, 8), 256, 0, stream>>>(qb, kb, vb, attn, ctxb);
    outproj_kernel<<<dim3(32, 8), 256, 0, stream>>>(ctxb, wo, bo, out);
}